// Round 3
// baseline (167.577 us; speedup 1.0000x reference)
//
#include <hip/hip_runtime.h>
#include <hip/hip_bf16.h>

using bf16 = __hip_bfloat16;
typedef __attribute__((ext_vector_type(8))) short s16x8;
typedef __attribute__((ext_vector_type(4))) short s16x4;
typedef __attribute__((ext_vector_type(4))) float f32x4;
typedef unsigned int u32;

__device__ __forceinline__ float b2f(short u) {
    union { float f; u32 i; } x; x.i = ((u32)(unsigned short)u) << 16; return x.f;
}
__device__ __forceinline__ short f2b(float f) {
    bf16 h = (bf16)f; return *(short*)&h;
}

// async global(16B/lane) -> LDS (wave-uniform base + lane*16, linear)
__device__ __forceinline__ void g2l16(const void* g, void* l) {
    __builtin_amdgcn_global_load_lds(
        (const __attribute__((address_space(1))) void*)g,
        (__attribute__((address_space(3))) void*)l, 16, 0, 0);
}

// ---- convert fp32 -> bf16. R16: now ALSO converts q/k/v (13 tensors) so the
// proj GEMM A-side can use global_load_lds like everything else. Numerically
// identical: old path applied the same f2b rounding at stage time. ----
struct CvtArgs { const float* src[13]; bf16* dst[13]; int n[13]; int bb[14]; };
__global__ __launch_bounds__(256)
void convert_kernel(CvtArgs a) {
    const int blk = blockIdx.x;
    int s = 0;
    while (s < 12 && blk >= a.bb[s + 1]) ++s;
    const int base = (blk - a.bb[s]) * 1024 + threadIdx.x * 4;
    if (base >= a.n[s]) return;            // all n % 4 == 0
    float4 v = *(const float4*)(a.src[s] + base);
    ushort4 o;
    o.x = (unsigned short)f2b(v.x); o.y = (unsigned short)f2b(v.y);
    o.z = (unsigned short)f2b(v.z); o.w = (unsigned short)f2b(v.w);
    *(ushort4*)(a.dst[s] + base) = o;
}

// ---- R16 GEMM core: C = A @ W^T + bias, all-bf16, triple-buffered LDS,
// counted s_waitcnt vmcnt(N) (never drains the just-issued prefetch) + raw
// s_barrier: one barrier/step, load latency spans a full K-step.
// Race safety: buf (k+2)%3 was last READ in step k-1, protected by the
// lgkmcnt(0)+barrier ending step k-1; per-wave vmcnt(NV) + barrier makes all
// waves' tile-(k+1) DMA visible before step k+1 reads it. ----
template<int BM, int BN, bool OUT_F32>
__device__ __forceinline__ void gemm3(
    const bf16* __restrict__ A, const bf16* __restrict__ W,
    const bf16* __restrict__ bias, void* __restrict__ out,
    int m0, int n0, int N, int K, bf16* lA, bf16* lB) {
    constexpr int WM = BM / 2, WN = BN / 2, FM = WM / 16, FN = WN / 16;
    constexpr int CA = BM / 64, CB = BN / 64;     // gl_lds instrs per wave per tile
    constexpr int ASZ = BM * 32, BSZ = BN * 32;   // elems per buffer
    constexpr int NV = CA + CB;                   // vm ops/wave/tile (2 or 3)
    const int tid = threadIdx.x;
    const int wave = tid >> 6, lane = tid & 63;
    const int wr = wave >> 1, wc = wave & 1;
    const int quad = lane >> 4, lm = lane & 15;

    auto issue = [&](int k0, int buf) {
#pragma unroll
        for (int c = 0; c < CA; ++c) {
            const int sl = c * 256 + tid, row = sl >> 2, col = (sl & 3) * 8;
            g2l16(A + (size_t)(m0 + row) * K + k0 + col,
                  lA + buf * ASZ + (c * 256 + wave * 64) * 8);
        }
#pragma unroll
        for (int c = 0; c < CB; ++c) {
            const int sl = c * 256 + tid, row = sl >> 2, col = (sl & 3) * 8;
            g2l16(W + (size_t)(n0 + row) * K + k0 + col,
                  lB + buf * BSZ + (c * 256 + wave * 64) * 8);
        }
    };

    const int ns = K / 32;
    f32x4 acc[FM][FN] = {};

    issue(0, 0); issue(32, 1);                      // 2*NV outstanding
    if constexpr (NV == 2) asm volatile("s_waitcnt vmcnt(2)" ::: "memory");
    else                   asm volatile("s_waitcnt vmcnt(3)" ::: "memory");
    __builtin_amdgcn_sched_barrier(0);
    __builtin_amdgcn_s_barrier();
    __builtin_amdgcn_sched_barrier(0);

    int cur = 0;
    for (int k = 0; k < ns; ++k) {
        if (k + 2 < ns) {                           // prefetch into freed buffer
            int b2 = cur + 2; if (b2 >= 3) b2 -= 3;
            issue((k + 2) * 32, b2);
        }
        const bf16* cA = lA + cur * ASZ;
        const bf16* cB = lB + cur * BSZ;
        s16x8 af[FM], bf_[FN];
#pragma unroll
        for (int i = 0; i < FM; ++i)
            af[i] = *(const s16x8*)&cA[(wr * WM + i * 16 + lm) * 32 + quad * 8];
#pragma unroll
        for (int j = 0; j < FN; ++j)
            bf_[j] = *(const s16x8*)&cB[(wc * WN + j * 16 + lm) * 32 + quad * 8];
#pragma unroll
        for (int i = 0; i < FM; ++i)
#pragma unroll
            for (int j = 0; j < FN; ++j)
                acc[i][j] = __builtin_amdgcn_mfma_f32_16x16x32_bf16(af[i], bf_[j], acc[i][j], 0, 0, 0);
        if (k + 2 < ns) {
            // wait tile k+1 only (tile k+2 stays in flight across the barrier)
            if constexpr (NV == 2) asm volatile("s_waitcnt vmcnt(2) lgkmcnt(0)" ::: "memory");
            else                   asm volatile("s_waitcnt vmcnt(3) lgkmcnt(0)" ::: "memory");
            __builtin_amdgcn_sched_barrier(0);
            __builtin_amdgcn_s_barrier();
            __builtin_amdgcn_sched_barrier(0);
        } else if (k + 1 < ns) {                    // tail: drain everything once
            asm volatile("s_waitcnt vmcnt(0) lgkmcnt(0)" ::: "memory");
            __builtin_amdgcn_sched_barrier(0);
            __builtin_amdgcn_s_barrier();
            __builtin_amdgcn_sched_barrier(0);
        }
        cur += 1; if (cur >= 3) cur = 0;
    }
#pragma unroll
    for (int i = 0; i < FM; ++i) {
        const int rbase = m0 + wr * WM + i * 16 + quad * 4;
#pragma unroll
        for (int j = 0; j < FN; ++j) {
            const int col = n0 + wc * WN + j * 16 + lm;
            const float bv = (float)bias[col];
#pragma unroll
            for (int r = 0; r < 4; ++r) {
                float v = acc[i][j][r] + bv;
                size_t off = (size_t)(rbase + r) * N + col;
                if (OUT_F32) ((float*)out)[off] = v;
                else         ((bf16*)out)[off] = (bf16)v;
            }
        }
    }
}

// ---- fused Q/K/V projection: 768 blocks (3/CU), 128x64 tiles, XCD-swizzled.
// A-side now pre-converted bf16 -> full gl_lds staging. ----
__global__ __launch_bounds__(256)
void proj_kernel(const bf16* __restrict__ qb, const bf16* __restrict__ kb,
                 const bf16* __restrict__ vb,
                 const bf16* __restrict__ Qkc, const bf16* __restrict__ Kkc,
                 const bf16* __restrict__ Vkc,
                 const bf16* __restrict__ Qbc, const bf16* __restrict__ Kbc,
                 const bf16* __restrict__ Vbc,
                 bf16* __restrict__ qp, bf16* __restrict__ kp,
                 bf16* __restrict__ vp) {
    __shared__ __align__(16) bf16 lA[3 * 128 * 32];   // triple-buffered
    __shared__ __align__(16) bf16 lB[3 * 64 * 32];
    const int L = blockIdx.x, xcd = L & 7, i = L >> 3;
    const int m0 = (xcd * 2 + i / 48) * 128;
    const int nid = i % 48;
    if (nid < 10)
        gemm3<128, 64, false>(qb, Qkc, Qbc, qp, m0, nid * 64, 640, 640, lA, lB);
    else if (nid < 20)
        gemm3<128, 64, false>(kb, Kkc, Kbc, kp, m0, (nid - 10) * 64, 640, 640, lA, lB);
    else
        gemm3<128, 64, false>(vb, Vkc, Vbc, vp, m0, (nid - 20) * 64, 1792, 640, lA, lB);
}

// ---- collapse GEMM: 320 blocks of 64x64, K=1792. Only 1.25 blocks/CU ->
// latency-bound; the counted-vmcnt pipeline is the fix (load latency no
// longer drained at every barrier). ----
__global__ __launch_bounds__(256)
void collapse_kernel(const bf16* __restrict__ atn, const bf16* __restrict__ Ckc,
                     const bf16* __restrict__ Cbc, float* __restrict__ out) {
    __shared__ __align__(16) bf16 lA[3 * 64 * 32];
    __shared__ __align__(16) bf16 lB[3 * 64 * 32];
    const int L = blockIdx.x, xcd = L & 7, i = L >> 3;
    const int m0 = (xcd * 4 + i / 10) * 64;
    const int n0 = (i % 10) * 64;
    gemm3<64, 64, true>(atn, Ckc, Cbc, out, m0, n0, 640, 1792, lA, lB);
}

// ---- attention core: one block per position, XCD-swizzled. kp/qp bf16.
// R16: interior fast-path in Phases A & D (block-/group-uniform branch) drops
// per-tap bounds check + 64-bit pointer select. ----
__global__ __launch_bounds__(256)
void attn_v6(const bf16* __restrict__ qp, const bf16* __restrict__ kp,
             const bf16* __restrict__ vp,
             const bf16* __restrict__ Kbc, const bf16* __restrict__ Vbc,
             const bf16* __restrict__ Skc, const bf16* __restrict__ Sbc,
             bf16* __restrict__ atn) {
    const int pos = ((blockIdx.x & 7) << 8) | (blockIdx.x >> 3);  // XCD-contiguous
    const int b = pos >> 10, l = pos & 1023;
    const int t = threadIdx.x;
    __shared__ float qs[640];          // q kept fp32 in LDS (conflict-free reads)
    __shared__ float sc5[5 * 32];
    __shared__ float sc14[14 * 32];
    __shared__ float w14T[32 * 14];    // transposed: [tap][head]

    if (t < 80) {
        s16x8 qv = *(const s16x8*)((const short*)qp + (size_t)pos * 640 + t * 8);
#pragma unroll
        for (int r = 0; r < 8; ++r) qs[t * 8 + r] = b2f(qv[r]);
    }
    __syncthreads();

    // Phase A: score[s][j] = q[s].kwin[s][j]; 8 lanes/dot, 2x 16B k loads.
    {
        const int j = t >> 3, p = t & 7;
#pragma unroll
        for (int s = 0; s < 5; ++s) {
            const int dil = (s < 2) ? 1 : (1 << (s - 1));
            const int pl = (31 * dil) >> 1;
            const float* q = qs + s * 128 + p * 8;
            auto dot = [&](const short* kr) -> float {
                float a = 0.f;
#pragma unroll
                for (int g = 0; g < 2; ++g) {
                    s16x8 kv = *(const s16x8*)(kr + g * 64);
                    float4 q0 = *(const float4*)(q + g * 64);
                    float4 q1 = *(const float4*)(q + g * 64 + 4);
                    a += q0.x * b2f(kv[0]) + q0.y * b2f(kv[1])
                       + q0.z * b2f(kv[2]) + q0.w * b2f(kv[3])
                       + q1.x * b2f(kv[4]) + q1.y * b2f(kv[5])
                       + q1.z * b2f(kv[6]) + q1.w * b2f(kv[7]);
                }
                return a;
            };
            float acc;
            if (l - pl >= 0 && l + 31 * dil - pl < 1024) {      // block-uniform
                const short* kr = (const short*)kp
                    + (size_t)((b << 10) + l - pl + j * dil) * 640 + s * 128 + p * 8;
                acc = dot(kr);
            } else {
                const int row = l + j * dil - pl;
                const short* kr = (row >= 0 && row < 1024)
                    ? (const short*)kp + (size_t)((b << 10) | row) * 640 + s * 128 + p * 8
                    : (const short*)Kbc + s * 128 + p * 8;      // pad rows -> bias
                acc = dot(kr);
            }
            acc += __shfl_xor(acc, 1);
            acc += __shfl_xor(acc, 2);
            acc += __shfl_xor(acc, 4);
            if (p == 0) sc5[s * 32 + j] = acc;
        }
    }
    __syncthreads();

    // Phase B: supersample + positional resampling (448 outputs), vectorized Sk
    for (int idx = t; idx < 448; idx += 256) {
        const int h = idx >> 5;
        const int s = (h < 5) ? 0 : (h < 10) ? 1 : (h < 12) ? 2 : (h == 12) ? 3 : 4;
        const s16x8* sk = (const s16x8*)((const short*)Skc + idx * 32);
        const float* sc = sc5 + s * 32;
        float acc = b2f(((const short*)Sbc)[idx]);
#pragma unroll
        for (int g = 0; g < 4; ++g) {
            s16x8 kk = sk[g];
#pragma unroll
            for (int r = 0; r < 8; ++r) acc += sc[g * 8 + r] * b2f(kk[r]);
        }
        sc14[idx] = acc;
    }
    __syncthreads();

    // Phase C: softmax, 16 lanes/head (2 taps each), shuffle-reduce width 16
    if (t < 224) {
        const int h = t >> 4, u = t & 15;
        float s0 = sc14[h * 32 + u], s1 = sc14[h * 32 + u + 16];
        float mx = fmaxf(s0, s1);
#pragma unroll
        for (int m = 1; m < 16; m <<= 1) mx = fmaxf(mx, __shfl_xor(mx, m));
        float e0 = __expf(s0 - mx), e1 = __expf(s1 - mx);
        float sum = e0 + e1;
#pragma unroll
        for (int m = 1; m < 16; m <<= 1) sum += __shfl_xor(sum, m);
        float inv = 1.f / sum;
        w14T[u * 14 + h] = e0 * inv;
        w14T[(u + 16) * 14 + h] = e1 * inv;
    }
    __syncthreads();

    // Phase D: attn[h][d8] = sum_j w[j][h] * vwin[h][j][d8]
    if (t < 224) {
        const int h = t >> 4, d8 = (t & 15) * 8;
        const int dil = (h < 10) ? 1 : (h < 12) ? 2 : (h == 12) ? 4 : 8;
        const int pl = (31 * dil) >> 1;
        const int col = h * 128 + d8;
        float acc[8] = {};
        if (l - pl >= 0 && l + 31 * dil - pl < 1024) {          // 16-lane-uniform
            const short* src = (const short*)vp
                + (size_t)((b << 10) + l - pl) * 1792 + col;
            const size_t stride = (size_t)dil * 1792;
#pragma unroll
            for (int j = 0; j < 32; ++j) {
                s16x8 v8 = *(const s16x8*)(src + j * stride);
                const float w = w14T[j * 14 + h];
#pragma unroll
                for (int r = 0; r < 8; ++r) acc[r] += w * b2f(v8[r]);
            }
        } else {
#pragma unroll
            for (int j = 0; j < 32; ++j) {
                const int row = l + j * dil - pl;
                const short* src = (row >= 0 && row < 1024)
                    ? (const short*)vp + (size_t)((b << 10) | row) * 1792 + col
                    : (const short*)Vbc + col;     // pad rows project the bias
                s16x8 v8 = *(const s16x8*)src;
                const float w = w14T[j * 14 + h];
#pragma unroll
                for (int r = 0; r < 8; ++r) acc[r] += w * b2f(v8[r]);
            }
        }
        union { uint4 u; short h16[8]; } o;
#pragma unroll
        for (int r = 0; r < 8; ++r) o.h16[r] = f2b(acc[r]);
        *(uint4*)((short*)atn + (size_t)pos * 1792 + col) = o.u;
    }
}

extern "C" void kernel_launch(void* const* d_in, const int* in_sizes, int n_in,
                              void* d_out, int out_size, void* d_ws, size_t ws_size,
                              hipStream_t stream) {
    const int M = 2048;
    char* w = (char*)d_ws;
    size_t off = 0;
    auto alloc = [&](size_t bytes) -> char* {
        off = (off + 255) & ~(size_t)255;
        char* p = w + off; off += bytes; return p;
    };
    bf16* Qkc = (bf16*)alloc(409600 * 2);
    bf16* Qbc = (bf16*)alloc(640 * 2);
    bf16* Kkc = (bf16*)alloc(409600 * 2);
    bf16* Kbc = (bf16*)alloc(640 * 2);
    bf16* Vkc = (bf16*)alloc(1146880 * 2);
    bf16* Vbc = (bf16*)alloc(1792 * 2);
    bf16* Skc = (bf16*)alloc(14336 * 2);
    bf16* Sbc = (bf16*)alloc(448 * 2);
    bf16* Ckc = (bf16*)alloc(1146880 * 2);
    bf16* Cbc = (bf16*)alloc(640 * 2);
    bf16* qb  = (bf16*)alloc((size_t)M * 640 * 2);
    bf16* kb  = (bf16*)alloc((size_t)M * 640 * 2);
    bf16* vb  = (bf16*)alloc((size_t)M * 640 * 2);
    bf16* qp  = (bf16*)alloc((size_t)M * 640 * 2);
    bf16* kp  = (bf16*)alloc((size_t)M * 640 * 2);
    bf16* vp  = (bf16*)alloc((size_t)M * 1792 * 2);
    bf16* atn = (bf16*)alloc((size_t)M * 1792 * 2);

    CvtArgs ca;
    bf16* dsts[13] = {Qkc, Qbc, Kkc, Kbc, Vkc, Vbc, Skc, Sbc, Ckc, Cbc, qb, kb, vb};
    const int ns[13] = {409600, 640, 409600, 640, 1146880, 1792, 14336, 448,
                        1146880, 640, 1310720, 1310720, 1310720};
    int cum = 0;
    for (int i = 0; i < 13; ++i) {
        ca.src[i] = (const float*)d_in[i < 10 ? 3 + i : i - 10];
        ca.dst[i] = dsts[i];
        ca.n[i] = ns[i];
        ca.bb[i] = cum;
        cum += (ns[i] + 1023) / 1024;
    }
    ca.bb[13] = cum;

    dim3 blk(256);
    convert_kernel<<<dim3(cum), blk, 0, stream>>>(ca);
    proj_kernel<<<dim3(768), blk, 0, stream>>>(
        qb, kb, vb, Qkc, Kkc, Vkc, Qbc, Kbc, Vbc, qp, kp, vp);
    attn_v6<<<dim3(2048), blk, 0, stream>>>(qp, kp, vp, Kbc, Vbc, Skc, Sbc, atn);
    collapse_kernel<<<dim3(320), blk, 0, stream>>>(atn, Ckc, Cbc, (float*)d_out);
}